// Round 19
// baseline (116.392 us; speedup 1.0000x reference)
//
#include <hip/hip_runtime.h>
#include <math.h>

#define NB 16
#define NPAIR 8
#define NBINS 725
#define NPIX (1024*1024)

// Skewed LDS slot map: slot(idx,c) = idx*9 + c + (idx>>5). Mirror rows use
// idx in [0,513] -> slots <= 4640. Hist accumulators overlay the dead tile
// region at HSOFF (2 reps x 2 x NBINS = 2900 <= 9248-4672).
#define SLOT(idx, c) ((idx)*9 + (c) + ((idx)>>5))
#define SH_SIZE 9248
#define HSOFF 4672
#define C45 0.70710678118654752f

// bf16 pack/unpack (RNE, unbiased).
__device__ __forceinline__ unsigned bf16rn(float f) {
    unsigned u = __float_as_uint(f);
    return (u + 0x7FFFu + ((u >> 16) & 1u)) >> 16;
}
__device__ __forceinline__ unsigned pk2(float2 v) {
    return bf16rn(v.x) | (bf16rn(v.y) << 16);
}
__device__ __forceinline__ float2 up2(unsigned v) {
    return make_float2(__uint_as_float(v << 16), __uint_as_float(v & 0xFFFF0000u));
}

__device__ __forceinline__ constexpr int rev5(int j) {
    return ((j&1)<<4) | ((j&2)<<2) | (j&4) | ((j&8)>>2) | ((j&16)>>4);
}

// In-register 32-point FFT with compile-time twiddle specialization.
__device__ __forceinline__ void fft32(float2* r) {
    const float wr[16] = {1.f, 0.98078528f, 0.92387953f, 0.83146961f,
                          0.70710678f, 0.55557023f, 0.38268343f, 0.19509032f,
                          0.f, -0.19509032f, -0.38268343f, -0.55557023f,
                          -0.70710678f, -0.83146961f, -0.92387953f, -0.98078528f};
    const float wi[16] = {0.f, -0.19509032f, -0.38268343f, -0.55557023f,
                          -0.70710678f, -0.83146961f, -0.92387953f, -0.98078528f,
                          -1.f, -0.98078528f, -0.92387953f, -0.83146961f,
                          -0.70710678f, -0.55557023f, -0.38268343f, -0.19509032f};
    #pragma unroll
    for (int s = 1; s <= 5; ++s) {
        const int half = 1 << (s - 1);
        #pragma unroll
        for (int g = 0; g < 32; g += (1 << s)) {
            #pragma unroll
            for (int j = 0; j < half; ++j) {
                const int a = j << (5 - s);
                int i1 = g + j, i2 = i1 + half;
                float2 u = r[i1], v = r[i2], vw;
                if (a == 0)       vw = v;
                else if (a == 8)  vw = make_float2(v.y, -v.x);
                else if (a == 4)  vw = make_float2(C45 * (v.x + v.y), C45 * (v.y - v.x));
                else if (a == 12) vw = make_float2(C45 * (v.y - v.x), -C45 * (v.x + v.y));
                else {
                    const float cw = wr[a], sw = wi[a];
                    vw = make_float2(v.x * cw - v.y * sw, v.x * sw + v.y * cw);
                }
                r[i1] = make_float2(u.x + vw.x, u.y + vw.y);
                r[i2] = make_float2(u.x - vw.x, u.y - vw.y);
            }
        }
    }
}

// Twiddle by W_1024^(n1*k2), k2 = 0..31, via one sincos + recurrence.
__device__ __forceinline__ void twiddle1024(float2* r, int n1) {
    float sn, cs;
    sincosf((float)n1 * -0.006135923151542565f, &sn, &cs);
    float wx = 1.f, wy = 0.f;
    #pragma unroll
    for (int k2 = 0; k2 < 32; ++k2) {
        float2 s = r[k2];
        r[k2] = make_float2(s.x * wx - s.y * wy, s.x * wy + s.y * wx);
        float nx = wx * cs - wy * sn;
        wy = wx * sn + wy * cs;
        wx = nx;
    }
}

__device__ __forceinline__ int ibin(int d2) {
    int bin = (int)sqrtf((float)d2);
    if ((bin + 1) * (bin + 1) <= d2) ++bin;
    else if (bin * bin > d2) --bin;
    return bin;
}

// Mirror-paired column groups (bijection over 0..1023 across k=0..127).
__device__ __forceinline__ int col_of(int k, int c) {
    if (k == 0) return (c < 4) ? c : ((c == 4) ? 512 : 1028 - c);
    int a = k << 2;
    return (c < 4) ? (a + c) : (1017 + c - a);
}
__device__ __forceinline__ int mir_of(int k, int c) {
    if (k == 0) return (c == 0 || c == 4) ? c : ((c < 4) ? c + 4 : c - 4);
    return 7 - c;
}

// Pass 1: row FFTs (four-step 32x32), output TRANSPOSED as packed bf16x2:
// spec_T[p][x][y]. p==0 blocks also build the geometry count hist.
__global__ __launch_bounds__(256, 4) void fft_rows(const float* __restrict__ in,
                                                   unsigned* __restrict__ spec,
                                                   float* __restrict__ cntp) {
    __shared__ unsigned sh[SH_SIZE];
    __shared__ float hc[NBINS];
    int tid = threadIdx.x, blk = blockIdx.x;
    int p = blk >> 7, y0 = (blk & 127) << 3;
    if (p == 0)
        for (int i = tid; i < NBINS; i += 256) hc[i] = 0.f;
    int n1 = tid & 31, c = tid >> 5;
    const float* xr = in + (((size_t)(2 * p)) << 20) + ((size_t)(y0 + c) << 10);
    const float* yr = xr + (1u << 20);
    float2 r[32];
    #pragma unroll
    for (int j = 0; j < 32; ++j) {
        int n = n1 + (rev5(j) << 5);
        r[j] = make_float2(xr[n], yr[n]);
    }
    fft32(r);
    twiddle1024(r, n1);
    int sb = 9 * n1 + c;
    #pragma unroll
    for (int k2 = 0; k2 < 32; ++k2) sh[sb + 289 * k2] = pk2(r[k2]);
    __syncthreads();
    int k2 = tid & 31;
    int rb = 289 * k2 + c;
    #pragma unroll
    for (int j = 0; j < 32; ++j) r[j] = up2(sh[rb + 9 * rev5(j)]);
    fft32(r);
    __syncthreads();
    int wb = 9 * k2 + c;
    #pragma unroll
    for (int k1 = 0; k1 < 32; ++k1) sh[wb + 289 * k1] = pk2(r[k1]);
    __syncthreads();
    unsigned* base = spec + (((size_t)p) << 20);
    for (int rep = 0; rep < 32; ++rep) {
        int idx = (rep << 8) + tid;
        int kcol = idx >> 3, cc = idx & 7;
        base[((size_t)kcol << 10) + y0 + cc] = sh[SLOT(kcol, cc)];
    }
    // ---- counts phase (p==0 blocks only; uniform branch) ----
    if (p == 0) {
        int g = blk;                          // 0..127
        int row = (g << 2) + (tid >> 6);      // 4 rows/block, 0..511
        int xb = (tid & 63) << 4;             // run of 16 x
        int dy = row - 512, dy2 = dy * dy;
        int curbin = -1;
        float a = 0.f;
        #pragma unroll 4
        for (int j = 0; j < 16; ++j) {
            int x = xb + j;
            float w = 2.f;
            if (row == 0) w = (x > 512 || x == 0) ? 0.f : ((x == 512) ? 1.f : 2.f);
            int dx = x - 512;
            int bin = ibin(dy2 + dx * dx);
            if (bin == curbin) a += w;
            else {
                if (curbin >= 0 && a != 0.f) atomicAdd(&hc[curbin], a);
                curbin = bin; a = w;
            }
        }
        if (curbin >= 0 && a != 0.f) atomicAdd(&hc[curbin], a);
        if (g == 0) {                         // row 512
            int xb2 = tid << 2;
            int curb = -1;
            float aa = 0.f;
            #pragma unroll
            for (int j = 0; j < 4; ++j) {
                int xx = xb2 + j;
                if (xx > 512) continue;
                float w = ((xx & 511) == 0) ? 1.f : 2.f;
                int bin = 512 - xx;
                if (bin == curb) aa += w;
                else {
                    if (curb >= 0 && aa != 0.f) atomicAdd(&hc[curb], aa);
                    curb = bin; aa = w;
                }
            }
            if (curb >= 0 && aa != 0.f) atomicAdd(&hc[curb], aa);
        }
        __syncthreads();
        for (int i = tid; i < NBINS; i += 256)
            cntp[(size_t)g * NBINS + i] = hc[i];
    }
}

// Pass 2 (FUSED, 40KB LDS -> 4 blocks/CU): column FFTs + Hermitian powers +
// radial hist. Powers computed from round-2 REGISTERS + mirror-row LDS;
// hist accumulators overlay the dead tile region. No full-spectrum store.
__global__ __launch_bounds__(256, 4) void fft_cols_hist(const unsigned* __restrict__ spec,
                                                        float* __restrict__ s2buf,
                                                        float* __restrict__ partial) {
    __shared__ unsigned sh[SH_SIZE];
    __shared__ float wred[8];
    float* hs = (float*)(sh + HSOFF);     // [2 reps][2][NBINS]
    int tid = threadIdx.x, blk = blockIdx.x;
    int p = blk >> 7, k = blk & 127;
    int n1 = tid & 31, c = tid >> 5;
    const unsigned* base = spec + (((size_t)p) << 20);
    const unsigned* colp = base + ((size_t)col_of(k, c) << 10);
    float2 r[32];
    #pragma unroll
    for (int j = 0; j < 32; ++j) r[j] = up2(colp[n1 + (rev5(j) << 5)]);
    fft32(r);
    twiddle1024(r, n1);
    int sb = 9 * n1 + c;
    #pragma unroll
    for (int q = 0; q < 32; ++q) sh[sb + 289 * q] = pk2(r[q]);
    __syncthreads();
    int k2 = tid & 31;
    int rb = 289 * k2 + c;
    #pragma unroll
    for (int j = 0; j < 32; ++j) r[j] = up2(sh[rb + 9 * rev5(j)]);
    __syncthreads();                      // exchange reads done; tile reusable
    fft32(r);
    // stage mirror rows: row 0 -> slot row 0; rows 512..1023 -> slot row-511
    if (k2 == 0) sh[SLOT(0, c)] = pk2(r[0]);
    #pragma unroll
    for (int k1 = 16; k1 < 32; ++k1)
        sh[SLOT(k2 + (k1 << 5) - 511, c)] = pk2(r[k1]);
    // zero hist accumulators (dead tile region)
    for (int i = tid; i < 4 * NBINS; i += 256) hs[i] = 0.f;
    __syncthreads();
    // ---- powers from registers + mirror-LDS; bin directly; s2 acc ----
    const float inv = 1.0f / (float)NPIX;
    int x = col_of(k, c), mc = mir_of(k, c);
    bool xhi = (x > 512), xs = ((x & 511) == 0);
    int dxv = x - 512, dx2 = dxv * dxv;
    float* h0 = hs + ((tid >> 6) & 1) * (2 * NBINS);
    float* h1 = h0 + NBINS;
    float s2e = 0.f, s2o = 0.f;
    #pragma unroll
    for (int k1 = 0; k1 < 17; ++k1) {
        int ky = k2 + (k1 << 5);
        if (ky > 512) break;              // only k2==0 reaches k1==16
        bool ek = ((ky & 511) == 0);
        float w = 2.f;
        if (ek) w = xhi ? 0.f : (xs ? 1.f : 2.f);
        if (ky == 0 && x == 0) w = 0.f;
        int my = (1024 - ky) & 1023;
        int mi = (my == 0) ? 0 : my - 511;
        float2 f1 = r[k1];
        float2 f2 = up2(sh[SLOT(mi, mc)]);
        float xrr = 0.5f * (f1.x + f2.x), xii = 0.5f * (f1.y - f2.y);
        float yrr = 0.5f * (f1.y + f2.y), yii = 0.5f * (f2.x - f1.x);
        float pe = (xrr * xrr + xii * xii) * inv;
        float po = (yrr * yrr + yii * yii) * inv;
        float v0 = w * pe, v1 = w * po;
        s2e += v0 * pe;
        s2o += v1 * po;
        int dy = ky - 512;
        int bin = ibin(dy * dy + dx2);
        atomicAdd(&h0[bin], v0);
        atomicAdd(&h1[bin], v1);
    }
    // wave s2 reduce + wred store (before the barrier that publishes hs)
    #pragma unroll
    for (int off = 32; off > 0; off >>= 1) {
        s2e += __shfl_down(s2e, off);
        s2o += __shfl_down(s2o, off);
    }
    if ((tid & 63) == 0) { wred[tid >> 6] = s2e; wred[4 + (tid >> 6)] = s2o; }
    __syncthreads();
    if (tid == 0) s2buf[2 * blk]     = wred[0] + wred[1] + wred[2] + wred[3];
    if (tid == 1) s2buf[2 * blk + 1] = wred[4] + wred[5] + wred[6] + wred[7];
    // coalesced partial store: partial[b][k][bin], b = 2p / 2p+1
    float* pe = partial + ((size_t)(2 * p) * 128 + k) * NBINS;
    float* po = partial + ((size_t)(2 * p + 1) * 128 + k) * NBINS;
    for (int i = tid; i < NBINS; i += 256) {
        pe[i] = hs[i] + hs[2 * NBINS + i];
        po[i] = hs[NBINS + i] + hs[3 * NBINS + i];
    }
}

// Pass 3 (coalesced bands): block = (b, 256-bin band). Loops over 128 value
// slices and 128 count slices; every load is a contiguous row segment.
__global__ __launch_bounds__(256) void reduce_loss(const float* __restrict__ partial,
                                                   const float* __restrict__ cntp,
                                                   float* __restrict__ rowval) {
    int b = blockIdx.x / 3, band = blockIdx.x % 3;
    int bin = band * 256 + threadIdx.x;
    if (bin >= NBINS) return;
    const float* bp = partial + (size_t)b * 128 * NBINS + bin;
    float s = 0.f;
    #pragma unroll 8
    for (int k = 0; k < 128; ++k) s += bp[(size_t)k * NBINS];
    float cv = 0.f;
    #pragma unroll 8
    for (int g = 0; g < 128; ++g) cv += cntp[(size_t)g * NBINS + bin];
    rowval[b * NBINS + bin] = (cv > 0.f) ? s * s / cv : 0.f;
}

// Final: out = WA/B * (sum s2buf - sum rowval)
__global__ __launch_bounds__(256) void final_out(const float* __restrict__ s2buf,
                                                 const float* __restrict__ rowval,
                                                 float* __restrict__ out) {
    __shared__ float red[256];
    int tid = threadIdx.x;
    float acc = 0.f;
    for (int i = tid; i < NB * NBINS; i += 256) acc -= rowval[i];
    for (int i = tid; i < 2 * NPAIR * 128; i += 256) acc += s2buf[i];
    red[tid] = acc;
    __syncthreads();
    for (int s = 128; s > 0; s >>= 1) {
        if (tid < s) red[tid] += red[tid + s];
        __syncthreads();
    }
    if (tid == 0) out[0] = red[0] * (0.002f / 16.0f);
}

extern "C" void kernel_launch(void* const* d_in, const int* in_sizes, int n_in,
                              void* d_out, int out_size, void* d_ws, size_t ws_size,
                              hipStream_t stream) {
    const float* in = (const float*)d_in[0];
    float* out = (float*)d_out;
    char* ws = (char*)d_ws;

    unsigned* spec = (unsigned*)ws;                               // 32 MiB (bf16x2)
    float* s2buf   = (float*)(ws + ((size_t)NPAIR << 20) * sizeof(unsigned));
    float* rowval  = s2buf + 2 * NPAIR * 128;                     // 2048
    float* cntp    = rowval + NB * NBINS;                         // 11600
    float* partial = cntp + 128 * NBINS;                          // 92800
                                                                  // partial: 1484800

    fft_rows<<<NPAIR * 128, 256, 0, stream>>>(in, spec, cntp);
    fft_cols_hist<<<NPAIR * 128, 256, 0, stream>>>(spec, s2buf, partial);
    reduce_loss<<<NB * 3, 256, 0, stream>>>(partial, cntp, rowval);
    final_out<<<1, 256, 0, stream>>>(s2buf, rowval, out);
}

// Round 20
// 114.686 us; speedup vs baseline: 1.0149x; 1.0149x over previous
//
#include <hip/hip_runtime.h>
#include <hip/hip_bf16.h>
#include <math.h>

#define NB 16
#define NPAIR 8
#define NBINS 725
#define NPIX (1024*1024)

// Skewed LDS slot map: slot(idx,c) = idx*9 + c + (idx>>5). Stride-9 (odd)
// keeps FFT exchange patterns conflict-free; hist phase uses the
// (cl=tid>>5, chunk=tid&31) mapping which is conflict-free at b32.
#define SLOT(idx, c) ((idx)*9 + (c) + ((idx)>>5))
#define SH_SIZE 9248
#define C45 0.70710678118654752f

// bf16 pack via single v_cvt_pk_bf16_f32; unpack via shifts.
__device__ __forceinline__ unsigned pk2(float2 v) {
    __hip_bfloat162 b = __float22bfloat162_rn(v);
    return *(unsigned*)&b;
}
__device__ __forceinline__ float2 up2(unsigned v) {
    return make_float2(__uint_as_float(v << 16), __uint_as_float(v & 0xFFFF0000u));
}

__device__ __forceinline__ constexpr int rev5(int j) {
    return ((j&1)<<4) | ((j&2)<<2) | (j&4) | ((j&8)>>2) | ((j&16)>>4);
}

// In-register 32-point FFT with compile-time twiddle specialization.
__device__ __forceinline__ void fft32(float2* r) {
    const float wr[16] = {1.f, 0.98078528f, 0.92387953f, 0.83146961f,
                          0.70710678f, 0.55557023f, 0.38268343f, 0.19509032f,
                          0.f, -0.19509032f, -0.38268343f, -0.55557023f,
                          -0.70710678f, -0.83146961f, -0.92387953f, -0.98078528f};
    const float wi[16] = {0.f, -0.19509032f, -0.38268343f, -0.55557023f,
                          -0.70710678f, -0.83146961f, -0.92387953f, -0.98078528f,
                          -1.f, -0.98078528f, -0.92387953f, -0.83146961f,
                          -0.70710678f, -0.55557023f, -0.38268343f, -0.19509032f};
    #pragma unroll
    for (int s = 1; s <= 5; ++s) {
        const int half = 1 << (s - 1);
        #pragma unroll
        for (int g = 0; g < 32; g += (1 << s)) {
            #pragma unroll
            for (int j = 0; j < half; ++j) {
                const int a = j << (5 - s);
                int i1 = g + j, i2 = i1 + half;
                float2 u = r[i1], v = r[i2], vw;
                if (a == 0)       vw = v;
                else if (a == 8)  vw = make_float2(v.y, -v.x);
                else if (a == 4)  vw = make_float2(C45 * (v.x + v.y), C45 * (v.y - v.x));
                else if (a == 12) vw = make_float2(C45 * (v.y - v.x), -C45 * (v.x + v.y));
                else {
                    const float cw = wr[a], sw = wi[a];
                    vw = make_float2(v.x * cw - v.y * sw, v.x * sw + v.y * cw);
                }
                r[i1] = make_float2(u.x + vw.x, u.y + vw.y);
                r[i2] = make_float2(u.x - vw.x, u.y - vw.y);
            }
        }
    }
}

// Twiddle by W_1024^(n1*k2) from a precomputed global table (8KB, L1-hot).
// Replaces sincosf + 32-step serial recurrence with 31 independent loads.
__device__ __forceinline__ void twiddle1024(float2* r, int n1,
                                            const float2* __restrict__ tw) {
    const float2* wrow = tw + (n1 << 5);
    #pragma unroll
    for (int k2 = 1; k2 < 32; ++k2) {     // k2=0: w=1, skip
        float2 w = wrow[k2];
        float2 s = r[k2];
        r[k2] = make_float2(s.x * w.x - s.y * w.y, s.x * w.y + s.y * w.x);
    }
}

__device__ __forceinline__ int ibin(int d2) {
    int bin = (int)sqrtf((float)d2);
    if ((bin + 1) * (bin + 1) <= d2) ++bin;
    else if (bin * bin > d2) --bin;
    return bin;
}

// Mirror-paired column groups (bijection over 0..1023 across k=0..127).
__device__ __forceinline__ int col_of(int k, int c) {
    if (k == 0) return (c < 4) ? c : ((c == 4) ? 512 : 1028 - c);
    int a = k << 2;
    return (c < 4) ? (a + c) : (1017 + c - a);
}
__device__ __forceinline__ int mir_of(int k, int c) {
    if (k == 0) return (c == 0 || c == 4) ? c : ((c < 4) ? c + 4 : c - 4);
    return 7 - c;
}

// Setup: twiddle table tw[n1*32+k2] = exp(-i*2*pi*n1*k2/1024), f32.
__global__ __launch_bounds__(256) void make_tw(float2* __restrict__ tw) {
    int i = blockIdx.x * 256 + threadIdx.x;    // 0..1023
    int n1 = i >> 5, k2 = i & 31;
    float sn, cs;
    sincosf((float)(n1 * k2) * -0.006135923151542565f, &sn, &cs);
    tw[i] = make_float2(cs, sn);
}

// Pass 1: row FFTs (four-step 32x32), output TRANSPOSED as packed bf16x2:
// spec_T[p][x][y]. p==0 blocks also build the geometry count hist.
__global__ __launch_bounds__(256, 4) void fft_rows(const float* __restrict__ in,
                                                   unsigned* __restrict__ spec,
                                                   float* __restrict__ cntp,
                                                   const float2* __restrict__ tw) {
    __shared__ unsigned sh[SH_SIZE];
    __shared__ float hc[NBINS];
    int tid = threadIdx.x, blk = blockIdx.x;
    int p = blk >> 7, y0 = (blk & 127) << 3;
    if (p == 0)
        for (int i = tid; i < NBINS; i += 256) hc[i] = 0.f;
    int n1 = tid & 31, c = tid >> 5;
    const float* xr = in + (((size_t)(2 * p)) << 20) + ((size_t)(y0 + c) << 10);
    const float* yr = xr + (1u << 20);
    float2 r[32];
    #pragma unroll
    for (int j = 0; j < 32; ++j) {
        int n = n1 + (rev5(j) << 5);
        r[j] = make_float2(xr[n], yr[n]);
    }
    fft32(r);
    twiddle1024(r, n1, tw);
    int sb = 9 * n1 + c;
    #pragma unroll
    for (int k2 = 0; k2 < 32; ++k2) sh[sb + 289 * k2] = pk2(r[k2]);
    __syncthreads();
    int k2 = tid & 31;
    int rb = 289 * k2 + c;
    #pragma unroll
    for (int j = 0; j < 32; ++j) r[j] = up2(sh[rb + 9 * rev5(j)]);
    fft32(r);
    __syncthreads();
    int wb = 9 * k2 + c;
    #pragma unroll
    for (int k1 = 0; k1 < 32; ++k1) sh[wb + 289 * k1] = pk2(r[k1]);
    __syncthreads();
    unsigned* base = spec + (((size_t)p) << 20);
    for (int rep = 0; rep < 32; ++rep) {
        int idx = (rep << 8) + tid;
        int kcol = idx >> 3, cc = idx & 7;
        base[((size_t)kcol << 10) + y0 + cc] = sh[SLOT(kcol, cc)];
    }
    // ---- counts phase (p==0 blocks only; uniform branch) ----
    if (p == 0) {
        int g = blk;                          // 0..127
        int row = (g << 2) + (tid >> 6);      // 4 rows/block, 0..511
        int xb = (tid & 63) << 4;             // run of 16 x
        int dy = row - 512, dy2 = dy * dy;
        int curbin = -1;
        float a = 0.f;
        #pragma unroll 4
        for (int j = 0; j < 16; ++j) {
            int x = xb + j;
            float w = 2.f;
            if (row == 0) w = (x > 512 || x == 0) ? 0.f : ((x == 512) ? 1.f : 2.f);
            int dx = x - 512;
            int bin = ibin(dy2 + dx * dx);
            if (bin == curbin) a += w;
            else {
                if (curbin >= 0 && a != 0.f) atomicAdd(&hc[curbin], a);
                curbin = bin; a = w;
            }
        }
        if (curbin >= 0 && a != 0.f) atomicAdd(&hc[curbin], a);
        if (g == 0) {                         // row 512
            int xb2 = tid << 2;
            int curb = -1;
            float aa = 0.f;
            #pragma unroll
            for (int j = 0; j < 4; ++j) {
                int xx = xb2 + j;
                if (xx > 512) continue;
                float w = ((xx & 511) == 0) ? 1.f : 2.f;
                int bin = 512 - xx;
                if (bin == curb) aa += w;
                else {
                    if (curb >= 0 && aa != 0.f) atomicAdd(&hc[curb], aa);
                    curb = bin; aa = w;
                }
            }
            if (curb >= 0 && aa != 0.f) atomicAdd(&hc[curb], aa);
        }
        __syncthreads();
        for (int i = tid; i < NBINS; i += 256)
            cntp[(size_t)g * NBINS + i] = hc[i];
    }
}

// Pass 2 (FUSED): column FFTs + Hermitian powers + radial hist, spectrum in
// packed bf16x2 throughout.
__global__ __launch_bounds__(256, 3) void fft_cols_hist(const unsigned* __restrict__ spec,
                                                        float* __restrict__ s2buf,
                                                        float* __restrict__ partial,
                                                        const float2* __restrict__ tw) {
    __shared__ unsigned sh[SH_SIZE];
    __shared__ float hs0[NBINS], hs1[NBINS];
    __shared__ float wred[8];
    int tid = threadIdx.x, blk = blockIdx.x;
    int p = blk >> 7, k = blk & 127;
    for (int i = tid; i < NBINS; i += 256) { hs0[i] = 0.f; hs1[i] = 0.f; }
    int n1 = tid & 31, c = tid >> 5;
    const unsigned* base = spec + (((size_t)p) << 20);
    const unsigned* colp = base + ((size_t)col_of(k, c) << 10);
    float2 r[32];
    #pragma unroll
    for (int j = 0; j < 32; ++j) r[j] = up2(colp[n1 + (rev5(j) << 5)]);
    fft32(r);
    twiddle1024(r, n1, tw);
    int sb = 9 * n1 + c;
    #pragma unroll
    for (int q = 0; q < 32; ++q) sh[sb + 289 * q] = pk2(r[q]);
    __syncthreads();
    int k2 = tid & 31;
    int rb = 289 * k2 + c;
    #pragma unroll
    for (int j = 0; j < 32; ++j) r[j] = up2(sh[rb + 9 * rev5(j)]);
    __syncthreads();                      // exchange reads done; buffer reused
    fft32(r);
    // store full column spectrum: slot(k2 + 32*k1, c) = 9*k2 + c + 289*k1
    int wb = 9 * k2 + c;
    #pragma unroll
    for (int k1 = 0; k1 < 32; ++k1) sh[wb + 289 * k1] = pk2(r[k1]);
    __syncthreads();
    // ---- hist phase: cl = tid>>5 (column), chunk = tid&31 (16-ky run) ----
    const float inv = 1.0f / (float)NPIX;
    int cl = tid >> 5, chunk = tid & 31;
    int xcol = col_of(k, cl), mc = mir_of(k, cl);
    int dxv = xcol - 512, dx2 = dxv * dxv;
    bool xs = ((xcol & 511) == 0), xhi = (xcol > 512);
    float s2e = 0.f, s2o = 0.f;
    int curbin = -1;
    float a0 = 0.f, a1 = 0.f;
    int ky0 = chunk << 4;
    #pragma unroll 4
    for (int j = 0; j < 16; ++j) {
        int ky = ky0 + j;
        float w = 2.f;
        if (ky == 0) w = xhi ? 0.f : ((xcol == 0) ? 0.f : (xs ? 1.f : 2.f));
        int my = (1024 - ky) & 1023;
        float2 f1 = up2(sh[SLOT(ky, cl)]);
        float2 f2 = up2(sh[SLOT(my, mc)]);
        float xr = 0.5f * (f1.x + f2.x), xi = 0.5f * (f1.y - f2.y);
        float yr = 0.5f * (f1.y + f2.y), yi = 0.5f * (f2.x - f1.x);
        float pe = (xr * xr + xi * xi) * inv;
        float po = (yr * yr + yi * yi) * inv;
        int dy = ky - 512;
        int bin = ibin(dy * dy + dx2);
        float v0 = w * pe, v1 = w * po;
        s2e += v0 * pe;
        s2o += v1 * po;
        if (bin == curbin) { a0 += v0; a1 += v1; }
        else {
            if (curbin >= 0) { atomicAdd(&hs0[curbin], a0); atomicAdd(&hs1[curbin], a1); }
            curbin = bin; a0 = v0; a1 = v1;
        }
    }
    if (curbin >= 0) { atomicAdd(&hs0[curbin], a0); atomicAdd(&hs1[curbin], a1); }
    // ky = 512 row: one thread per column
    if ((tid & 31) == 0) {
        int cl2 = tid >> 5;
        int x2 = col_of(k, cl2);
        if (x2 <= 512) {
            int mc2 = mir_of(k, cl2);
            float w = ((x2 & 511) == 0) ? 1.f : 2.f;
            float2 f1 = up2(sh[SLOT(512, cl2)]);
            float2 f2 = up2(sh[SLOT(512, mc2)]);
            float xr = 0.5f * (f1.x + f2.x), xi = 0.5f * (f1.y - f2.y);
            float yr = 0.5f * (f1.y + f2.y), yi = 0.5f * (f2.x - f1.x);
            float pe = (xr * xr + xi * xi) * inv;
            float po = (yr * yr + yi * yi) * inv;
            float v0 = w * pe, v1 = w * po;
            s2e += v0 * pe;
            s2o += v1 * po;
            int bin = (x2 < 512) ? 512 - x2 : 0;   // dy = 0, exact
            atomicAdd(&hs0[bin], v0);
            atomicAdd(&hs1[bin], v1);
        }
    }
    #pragma unroll
    for (int off = 32; off > 0; off >>= 1) {
        s2e += __shfl_down(s2e, off);
        s2o += __shfl_down(s2o, off);
    }
    if ((tid & 63) == 0) { wred[tid >> 6] = s2e; wred[4 + (tid >> 6)] = s2o; }
    __syncthreads();
    if (tid == 0) s2buf[2 * blk]     = wred[0] + wred[1] + wred[2] + wred[3];
    if (tid == 1) s2buf[2 * blk + 1] = wred[4] + wred[5] + wred[6] + wred[7];
    // coalesced partial store: partial[b][k][bin], b = 2p / 2p+1
    float* pe = partial + ((size_t)(2 * p) * 128 + k) * NBINS;
    float* po = partial + ((size_t)(2 * p + 1) * 128 + k) * NBINS;
    for (int i = tid; i < NBINS; i += 256) {
        pe[i] = hs0[i];
        po[i] = hs1[i];
    }
}

// Pass 3 (coalesced bands): block = (b, 256-bin band). Loops over 128 value
// slices and 128 count slices; every load is a contiguous row segment.
__global__ __launch_bounds__(256) void reduce_loss(const float* __restrict__ partial,
                                                   const float* __restrict__ cntp,
                                                   float* __restrict__ rowval) {
    int b = blockIdx.x / 3, band = blockIdx.x % 3;
    int bin = band * 256 + threadIdx.x;
    if (bin >= NBINS) return;
    const float* bp = partial + (size_t)b * 128 * NBINS + bin;
    float s = 0.f;
    #pragma unroll 8
    for (int k = 0; k < 128; ++k) s += bp[(size_t)k * NBINS];
    float cv = 0.f;
    #pragma unroll 8
    for (int g = 0; g < 128; ++g) cv += cntp[(size_t)g * NBINS + bin];
    rowval[b * NBINS + bin] = (cv > 0.f) ? s * s / cv : 0.f;
}

// Final: out = WA/B * (sum s2buf - sum rowval)
__global__ __launch_bounds__(256) void final_out(const float* __restrict__ s2buf,
                                                 const float* __restrict__ rowval,
                                                 float* __restrict__ out) {
    __shared__ float red[256];
    int tid = threadIdx.x;
    float acc = 0.f;
    for (int i = tid; i < NB * NBINS; i += 256) acc -= rowval[i];
    for (int i = tid; i < 2 * NPAIR * 128; i += 256) acc += s2buf[i];
    red[tid] = acc;
    __syncthreads();
    for (int s = 128; s > 0; s >>= 1) {
        if (tid < s) red[tid] += red[tid + s];
        __syncthreads();
    }
    if (tid == 0) out[0] = red[0] * (0.002f / 16.0f);
}

extern "C" void kernel_launch(void* const* d_in, const int* in_sizes, int n_in,
                              void* d_out, int out_size, void* d_ws, size_t ws_size,
                              hipStream_t stream) {
    const float* in = (const float*)d_in[0];
    float* out = (float*)d_out;
    char* ws = (char*)d_ws;

    unsigned* spec = (unsigned*)ws;                               // 32 MiB (bf16x2)
    float* s2buf   = (float*)(ws + ((size_t)NPAIR << 20) * sizeof(unsigned));
    float* rowval  = s2buf + 2 * NPAIR * 128;                     // 2048
    float* cntp    = rowval + NB * NBINS;                         // 11600
    float* partial = cntp + 128 * NBINS;                          // 92800
    float2* tw     = (float2*)(partial + (size_t)NB * 128 * NBINS); // 1024 float2

    make_tw<<<4, 256, 0, stream>>>(tw);
    fft_rows<<<NPAIR * 128, 256, 0, stream>>>(in, spec, cntp, tw);
    fft_cols_hist<<<NPAIR * 128, 256, 0, stream>>>(spec, s2buf, partial, tw);
    reduce_loss<<<NB * 3, 256, 0, stream>>>(partial, cntp, rowval);
    final_out<<<1, 256, 0, stream>>>(s2buf, rowval, out);
}

// Round 21
// 106.161 us; speedup vs baseline: 1.0964x; 1.0803x over previous
//
#include <hip/hip_runtime.h>
#include <hip/hip_bf16.h>
#include <math.h>

#define NB 16
#define NPAIR 8
#define NBINS 725
#define NPIX (1024*1024)

// Skewed LDS slot map: slot(idx,c) = idx*9 + c + (idx>>5). Stride-9 (odd)
// keeps FFT exchange patterns conflict-free; hist phase uses the
// (cl=tid>>5, chunk=tid&31) mapping which is conflict-free at b32.
#define SLOT(idx, c) ((idx)*9 + (c) + ((idx)>>5))
#define SH_SIZE 9248
#define C45 0.70710678118654752f

// bf16 pack via single v_cvt_pk_bf16_f32; unpack via shifts.
__device__ __forceinline__ unsigned pk2(float2 v) {
    __hip_bfloat162 b = __float22bfloat162_rn(v);
    return *(unsigned*)&b;
}
__device__ __forceinline__ float2 up2(unsigned v) {
    return make_float2(__uint_as_float(v << 16), __uint_as_float(v & 0xFFFF0000u));
}

__device__ __forceinline__ constexpr int rev5(int j) {
    return ((j&1)<<4) | ((j&2)<<2) | (j&4) | ((j&8)>>2) | ((j&16)>>4);
}

// In-register 32-point FFT with compile-time twiddle specialization.
__device__ __forceinline__ void fft32(float2* r) {
    const float wr[16] = {1.f, 0.98078528f, 0.92387953f, 0.83146961f,
                          0.70710678f, 0.55557023f, 0.38268343f, 0.19509032f,
                          0.f, -0.19509032f, -0.38268343f, -0.55557023f,
                          -0.70710678f, -0.83146961f, -0.92387953f, -0.98078528f};
    const float wi[16] = {0.f, -0.19509032f, -0.38268343f, -0.55557023f,
                          -0.70710678f, -0.83146961f, -0.92387953f, -0.98078528f,
                          -1.f, -0.98078528f, -0.92387953f, -0.83146961f,
                          -0.70710678f, -0.55557023f, -0.38268343f, -0.19509032f};
    #pragma unroll
    for (int s = 1; s <= 5; ++s) {
        const int half = 1 << (s - 1);
        #pragma unroll
        for (int g = 0; g < 32; g += (1 << s)) {
            #pragma unroll
            for (int j = 0; j < half; ++j) {
                const int a = j << (5 - s);
                int i1 = g + j, i2 = i1 + half;
                float2 u = r[i1], v = r[i2], vw;
                if (a == 0)       vw = v;
                else if (a == 8)  vw = make_float2(v.y, -v.x);
                else if (a == 4)  vw = make_float2(C45 * (v.x + v.y), C45 * (v.y - v.x));
                else if (a == 12) vw = make_float2(C45 * (v.y - v.x), -C45 * (v.x + v.y));
                else {
                    const float cw = wr[a], sw = wi[a];
                    vw = make_float2(v.x * cw - v.y * sw, v.x * sw + v.y * cw);
                }
                r[i1] = make_float2(u.x + vw.x, u.y + vw.y);
                r[i2] = make_float2(u.x - vw.x, u.y - vw.y);
            }
        }
    }
}

// Twiddle by W_1024^(n1*k2) from a precomputed global table (8KB, L1-hot).
// TRANSPOSED indexing tw[(k2<<5)+n1]: at each k2, lanes 0..31 read one
// consecutive 256B segment; lanes 32..63 broadcast the same addresses.
__device__ __forceinline__ void twiddle1024(float2* r, int n1,
                                            const float2* __restrict__ tw) {
    #pragma unroll
    for (int k2 = 1; k2 < 32; ++k2) {     // k2=0: w=1, skip
        float2 w = tw[(k2 << 5) + n1];
        float2 s = r[k2];
        r[k2] = make_float2(s.x * w.x - s.y * w.y, s.x * w.y + s.y * w.x);
    }
}

__device__ __forceinline__ int ibin(int d2) {
    int bin = (int)sqrtf((float)d2);
    if ((bin + 1) * (bin + 1) <= d2) ++bin;
    else if (bin * bin > d2) --bin;
    return bin;
}

// Mirror-paired column groups (bijection over 0..1023 across k=0..127).
__device__ __forceinline__ int col_of(int k, int c) {
    if (k == 0) return (c < 4) ? c : ((c == 4) ? 512 : 1028 - c);
    int a = k << 2;
    return (c < 4) ? (a + c) : (1017 + c - a);
}
__device__ __forceinline__ int mir_of(int k, int c) {
    if (k == 0) return (c == 0 || c == 4) ? c : ((c < 4) ? c + 4 : c - 4);
    return 7 - c;
}

// Setup: tw[32a+b] = exp(-i*2*pi*a*b/1024) (symmetric in a,b).
__global__ __launch_bounds__(256) void make_tw(float2* __restrict__ tw) {
    int i = blockIdx.x * 256 + threadIdx.x;    // 0..1023
    int a = i >> 5, b = i & 31;
    float sn, cs;
    sincosf((float)(a * b) * -0.006135923151542565f, &sn, &cs);
    tw[i] = make_float2(cs, sn);
}

// Pass 1: row FFTs (four-step 32x32), output TRANSPOSED as packed bf16x2:
// spec_T[p][x][y]. p==0 blocks also build the geometry count hist.
__global__ __launch_bounds__(256, 4) void fft_rows(const float* __restrict__ in,
                                                   unsigned* __restrict__ spec,
                                                   float* __restrict__ cntp,
                                                   const float2* __restrict__ tw) {
    __shared__ unsigned sh[SH_SIZE];
    __shared__ float hc[NBINS];
    int tid = threadIdx.x, blk = blockIdx.x;
    int p = blk >> 7, y0 = (blk & 127) << 3;
    if (p == 0)
        for (int i = tid; i < NBINS; i += 256) hc[i] = 0.f;
    int n1 = tid & 31, c = tid >> 5;
    const float* xr = in + (((size_t)(2 * p)) << 20) + ((size_t)(y0 + c) << 10);
    const float* yr = xr + (1u << 20);
    float2 r[32];
    #pragma unroll
    for (int j = 0; j < 32; ++j) {
        int n = n1 + (rev5(j) << 5);
        r[j] = make_float2(xr[n], yr[n]);
    }
    fft32(r);
    twiddle1024(r, n1, tw);
    int sb = 9 * n1 + c;
    #pragma unroll
    for (int k2 = 0; k2 < 32; ++k2) sh[sb + 289 * k2] = pk2(r[k2]);
    __syncthreads();
    int k2 = tid & 31;
    int rb = 289 * k2 + c;
    #pragma unroll
    for (int j = 0; j < 32; ++j) r[j] = up2(sh[rb + 9 * rev5(j)]);
    fft32(r);
    __syncthreads();
    int wb = 9 * k2 + c;
    #pragma unroll
    for (int k1 = 0; k1 < 32; ++k1) sh[wb + 289 * k1] = pk2(r[k1]);
    __syncthreads();
    unsigned* base = spec + (((size_t)p) << 20);
    for (int rep = 0; rep < 32; ++rep) {
        int idx = (rep << 8) + tid;
        int kcol = idx >> 3, cc = idx & 7;
        base[((size_t)kcol << 10) + y0 + cc] = sh[SLOT(kcol, cc)];
    }
    // ---- counts phase (p==0 blocks only; uniform branch) ----
    if (p == 0) {
        int g = blk;                          // 0..127
        int row = (g << 2) + (tid >> 6);      // 4 rows/block, 0..511
        int xb = (tid & 63) << 4;             // run of 16 x
        int dy = row - 512, dy2 = dy * dy;
        int curbin = -1;
        float a = 0.f;
        #pragma unroll 4
        for (int j = 0; j < 16; ++j) {
            int x = xb + j;
            float w = 2.f;
            if (row == 0) w = (x > 512 || x == 0) ? 0.f : ((x == 512) ? 1.f : 2.f);
            int dx = x - 512;
            int bin = ibin(dy2 + dx * dx);
            if (bin == curbin) a += w;
            else {
                if (curbin >= 0 && a != 0.f) atomicAdd(&hc[curbin], a);
                curbin = bin; a = w;
            }
        }
        if (curbin >= 0 && a != 0.f) atomicAdd(&hc[curbin], a);
        if (g == 0) {                         // row 512
            int xb2 = tid << 2;
            int curb = -1;
            float aa = 0.f;
            #pragma unroll
            for (int j = 0; j < 4; ++j) {
                int xx = xb2 + j;
                if (xx > 512) continue;
                float w = ((xx & 511) == 0) ? 1.f : 2.f;
                int bin = 512 - xx;
                if (bin == curb) aa += w;
                else {
                    if (curb >= 0 && aa != 0.f) atomicAdd(&hc[curb], aa);
                    curb = bin; aa = w;
                }
            }
            if (curb >= 0 && aa != 0.f) atomicAdd(&hc[curb], aa);
        }
        __syncthreads();
        for (int i = tid; i < NBINS; i += 256)
            cntp[(size_t)g * NBINS + i] = hc[i];
    }
}

// Pass 2 (FUSED): column FFTs + Hermitian powers + radial hist, spectrum in
// packed bf16x2 throughout.
__global__ __launch_bounds__(256, 3) void fft_cols_hist(const unsigned* __restrict__ spec,
                                                        float* __restrict__ s2buf,
                                                        float* __restrict__ partial,
                                                        const float2* __restrict__ tw) {
    __shared__ unsigned sh[SH_SIZE];
    __shared__ float hs0[NBINS], hs1[NBINS];
    __shared__ float wred[8];
    int tid = threadIdx.x, blk = blockIdx.x;
    int p = blk >> 7, k = blk & 127;
    for (int i = tid; i < NBINS; i += 256) { hs0[i] = 0.f; hs1[i] = 0.f; }
    int n1 = tid & 31, c = tid >> 5;
    const unsigned* base = spec + (((size_t)p) << 20);
    const unsigned* colp = base + ((size_t)col_of(k, c) << 10);
    float2 r[32];
    #pragma unroll
    for (int j = 0; j < 32; ++j) r[j] = up2(colp[n1 + (rev5(j) << 5)]);
    fft32(r);
    twiddle1024(r, n1, tw);
    int sb = 9 * n1 + c;
    #pragma unroll
    for (int q = 0; q < 32; ++q) sh[sb + 289 * q] = pk2(r[q]);
    __syncthreads();
    int k2 = tid & 31;
    int rb = 289 * k2 + c;
    #pragma unroll
    for (int j = 0; j < 32; ++j) r[j] = up2(sh[rb + 9 * rev5(j)]);
    __syncthreads();                      // exchange reads done; buffer reused
    fft32(r);
    // store full column spectrum: slot(k2 + 32*k1, c) = 9*k2 + c + 289*k1
    int wb = 9 * k2 + c;
    #pragma unroll
    for (int k1 = 0; k1 < 32; ++k1) sh[wb + 289 * k1] = pk2(r[k1]);
    __syncthreads();
    // ---- hist phase: cl = tid>>5 (column), chunk = tid&31 (16-ky run) ----
    const float inv = 1.0f / (float)NPIX;
    int cl = tid >> 5, chunk = tid & 31;
    int xcol = col_of(k, cl), mc = mir_of(k, cl);
    int dxv = xcol - 512, dx2 = dxv * dxv;
    bool xs = ((xcol & 511) == 0), xhi = (xcol > 512);
    float s2e = 0.f, s2o = 0.f;
    int curbin = -1;
    float a0 = 0.f, a1 = 0.f;
    int ky0 = chunk << 4;
    #pragma unroll 4
    for (int j = 0; j < 16; ++j) {
        int ky = ky0 + j;
        float w = 2.f;
        if (ky == 0) w = xhi ? 0.f : ((xcol == 0) ? 0.f : (xs ? 1.f : 2.f));
        int my = (1024 - ky) & 1023;
        float2 f1 = up2(sh[SLOT(ky, cl)]);
        float2 f2 = up2(sh[SLOT(my, mc)]);
        float xr = 0.5f * (f1.x + f2.x), xi = 0.5f * (f1.y - f2.y);
        float yr = 0.5f * (f1.y + f2.y), yi = 0.5f * (f2.x - f1.x);
        float pe = (xr * xr + xi * xi) * inv;
        float po = (yr * yr + yi * yi) * inv;
        int dy = ky - 512;
        int bin = ibin(dy * dy + dx2);
        float v0 = w * pe, v1 = w * po;
        s2e += v0 * pe;
        s2o += v1 * po;
        if (bin == curbin) { a0 += v0; a1 += v1; }
        else {
            if (curbin >= 0) { atomicAdd(&hs0[curbin], a0); atomicAdd(&hs1[curbin], a1); }
            curbin = bin; a0 = v0; a1 = v1;
        }
    }
    if (curbin >= 0) { atomicAdd(&hs0[curbin], a0); atomicAdd(&hs1[curbin], a1); }
    // ky = 512 row: one thread per column
    if ((tid & 31) == 0) {
        int cl2 = tid >> 5;
        int x2 = col_of(k, cl2);
        if (x2 <= 512) {
            int mc2 = mir_of(k, cl2);
            float w = ((x2 & 511) == 0) ? 1.f : 2.f;
            float2 f1 = up2(sh[SLOT(512, cl2)]);
            float2 f2 = up2(sh[SLOT(512, mc2)]);
            float xr = 0.5f * (f1.x + f2.x), xi = 0.5f * (f1.y - f2.y);
            float yr = 0.5f * (f1.y + f2.y), yi = 0.5f * (f2.x - f1.x);
            float pe = (xr * xr + xi * xi) * inv;
            float po = (yr * yr + yi * yi) * inv;
            float v0 = w * pe, v1 = w * po;
            s2e += v0 * pe;
            s2o += v1 * po;
            int bin = (x2 < 512) ? 512 - x2 : 0;   // dy = 0, exact
            atomicAdd(&hs0[bin], v0);
            atomicAdd(&hs1[bin], v1);
        }
    }
    #pragma unroll
    for (int off = 32; off > 0; off >>= 1) {
        s2e += __shfl_down(s2e, off);
        s2o += __shfl_down(s2o, off);
    }
    if ((tid & 63) == 0) { wred[tid >> 6] = s2e; wred[4 + (tid >> 6)] = s2o; }
    __syncthreads();
    if (tid == 0) s2buf[2 * blk]     = wred[0] + wred[1] + wred[2] + wred[3];
    if (tid == 1) s2buf[2 * blk + 1] = wred[4] + wred[5] + wred[6] + wred[7];
    // coalesced partial store: partial[b][k][bin], b = 2p / 2p+1
    float* pe = partial + ((size_t)(2 * p) * 128 + k) * NBINS;
    float* po = partial + ((size_t)(2 * p + 1) * 128 + k) * NBINS;
    for (int i = tid; i < NBINS; i += 256) {
        pe[i] = hs0[i];
        po[i] = hs1[i];
    }
}

// Pass 3 (coalesced bands): block = (b, 256-bin band). Loops over 128 value
// slices and 128 count slices; every load is a contiguous row segment.
__global__ __launch_bounds__(256) void reduce_loss(const float* __restrict__ partial,
                                                   const float* __restrict__ cntp,
                                                   float* __restrict__ rowval) {
    int b = blockIdx.x / 3, band = blockIdx.x % 3;
    int bin = band * 256 + threadIdx.x;
    if (bin >= NBINS) return;
    const float* bp = partial + (size_t)b * 128 * NBINS + bin;
    float s = 0.f;
    #pragma unroll 8
    for (int k = 0; k < 128; ++k) s += bp[(size_t)k * NBINS];
    float cv = 0.f;
    #pragma unroll 8
    for (int g = 0; g < 128; ++g) cv += cntp[(size_t)g * NBINS + bin];
    rowval[b * NBINS + bin] = (cv > 0.f) ? s * s / cv : 0.f;
}

// Final: out = WA/B * (sum s2buf - sum rowval)
__global__ __launch_bounds__(256) void final_out(const float* __restrict__ s2buf,
                                                 const float* __restrict__ rowval,
                                                 float* __restrict__ out) {
    __shared__ float red[256];
    int tid = threadIdx.x;
    float acc = 0.f;
    for (int i = tid; i < NB * NBINS; i += 256) acc -= rowval[i];
    for (int i = tid; i < 2 * NPAIR * 128; i += 256) acc += s2buf[i];
    red[tid] = acc;
    __syncthreads();
    for (int s = 128; s > 0; s >>= 1) {
        if (tid < s) red[tid] += red[tid + s];
        __syncthreads();
    }
    if (tid == 0) out[0] = red[0] * (0.002f / 16.0f);
}

extern "C" void kernel_launch(void* const* d_in, const int* in_sizes, int n_in,
                              void* d_out, int out_size, void* d_ws, size_t ws_size,
                              hipStream_t stream) {
    const float* in = (const float*)d_in[0];
    float* out = (float*)d_out;
    char* ws = (char*)d_ws;

    unsigned* spec = (unsigned*)ws;                               // 32 MiB (bf16x2)
    float* s2buf   = (float*)(ws + ((size_t)NPAIR << 20) * sizeof(unsigned));
    float* rowval  = s2buf + 2 * NPAIR * 128;                     // 2048
    float* cntp    = rowval + NB * NBINS;                         // 11600
    float* partial = cntp + 128 * NBINS;                          // 92800
    float2* tw     = (float2*)(partial + (size_t)NB * 128 * NBINS); // 1024 float2

    make_tw<<<4, 256, 0, stream>>>(tw);
    fft_rows<<<NPAIR * 128, 256, 0, stream>>>(in, spec, cntp, tw);
    fft_cols_hist<<<NPAIR * 128, 256, 0, stream>>>(spec, s2buf, partial, tw);
    reduce_loss<<<NB * 3, 256, 0, stream>>>(partial, cntp, rowval);
    final_out<<<1, 256, 0, stream>>>(s2buf, rowval, out);
}

// Round 22
// 99.597 us; speedup vs baseline: 1.1686x; 1.0659x over previous
//
#include <hip/hip_runtime.h>
#include <hip/hip_bf16.h>
#include <math.h>

#define NB 16
#define NPAIR 8
#define NBINS 725
#define NPIX (1024*1024)

// Skewed LDS slot map: slot(idx,c) = idx*9 + c + (idx>>5). Stride-9 (odd)
// keeps FFT exchange patterns conflict-free; hist phase uses the
// (cl=tid>>5, chunk=tid&31) mapping which is conflict-free at b32.
#define SLOT(idx, c) ((idx)*9 + (c) + ((idx)>>5))
#define SH_SIZE 9248
#define C45 0.70710678118654752f

// bf16 pack via single v_cvt_pk_bf16_f32; unpack via shifts.
__device__ __forceinline__ unsigned pk2(float2 v) {
    __hip_bfloat162 b = __float22bfloat162_rn(v);
    return *(unsigned*)&b;
}
__device__ __forceinline__ float2 up2(unsigned v) {
    return make_float2(__uint_as_float(v << 16), __uint_as_float(v & 0xFFFF0000u));
}

__device__ __forceinline__ constexpr int rev5(int j) {
    return ((j&1)<<4) | ((j&2)<<2) | (j&4) | ((j&8)>>2) | ((j&16)>>4);
}

// In-register 32-point FFT with compile-time twiddle specialization.
__device__ __forceinline__ void fft32(float2* r) {
    const float wr[16] = {1.f, 0.98078528f, 0.92387953f, 0.83146961f,
                          0.70710678f, 0.55557023f, 0.38268343f, 0.19509032f,
                          0.f, -0.19509032f, -0.38268343f, -0.55557023f,
                          -0.70710678f, -0.83146961f, -0.92387953f, -0.98078528f};
    const float wi[16] = {0.f, -0.19509032f, -0.38268343f, -0.55557023f,
                          -0.70710678f, -0.83146961f, -0.92387953f, -0.98078528f,
                          -1.f, -0.98078528f, -0.92387953f, -0.83146961f,
                          -0.70710678f, -0.55557023f, -0.38268343f, -0.19509032f};
    #pragma unroll
    for (int s = 1; s <= 5; ++s) {
        const int half = 1 << (s - 1);
        #pragma unroll
        for (int g = 0; g < 32; g += (1 << s)) {
            #pragma unroll
            for (int j = 0; j < half; ++j) {
                const int a = j << (5 - s);
                int i1 = g + j, i2 = i1 + half;
                float2 u = r[i1], v = r[i2], vw;
                if (a == 0)       vw = v;
                else if (a == 8)  vw = make_float2(v.y, -v.x);
                else if (a == 4)  vw = make_float2(C45 * (v.x + v.y), C45 * (v.y - v.x));
                else if (a == 12) vw = make_float2(C45 * (v.y - v.x), -C45 * (v.x + v.y));
                else {
                    const float cw = wr[a], sw = wi[a];
                    vw = make_float2(v.x * cw - v.y * sw, v.x * sw + v.y * cw);
                }
                r[i1] = make_float2(u.x + vw.x, u.y + vw.y);
                r[i2] = make_float2(u.x - vw.x, u.y - vw.y);
            }
        }
    }
}

// Twiddle (fft_rows): sincos + serial recurrence, no memory traffic.
__device__ __forceinline__ void twiddle_rec(float2* r, int n1) {
    float sn, cs;
    sincosf((float)n1 * -0.006135923151542565f, &sn, &cs);
    float wx = 1.f, wy = 0.f;
    #pragma unroll
    for (int k2 = 0; k2 < 32; ++k2) {
        float2 s = r[k2];
        r[k2] = make_float2(s.x * wx - s.y * wy, s.x * wy + s.y * wx);
        float nx = wx * cs - wy * sn;
        wy = wx * sn + wy * cs;
        wx = nx;
    }
}

// Twiddle (fft_cols_hist): precomputed global table, TRANSPOSED indexing
// tw[(k2<<5)+n1]: at each k2, lanes 0..31 read one consecutive 256B segment.
__device__ __forceinline__ void twiddle_tab(float2* r, int n1,
                                            const float2* __restrict__ tw) {
    #pragma unroll
    for (int k2 = 1; k2 < 32; ++k2) {     // k2=0: w=1, skip
        float2 w = tw[(k2 << 5) + n1];
        float2 s = r[k2];
        r[k2] = make_float2(s.x * w.x - s.y * w.y, s.x * w.y + s.y * w.x);
    }
}

__device__ __forceinline__ int ibin(int d2) {
    int bin = (int)sqrtf((float)d2);
    if ((bin + 1) * (bin + 1) <= d2) ++bin;
    else if (bin * bin > d2) --bin;
    return bin;
}

// Mirror-paired column groups (bijection over 0..1023 across k=0..127).
__device__ __forceinline__ int col_of(int k, int c) {
    if (k == 0) return (c < 4) ? c : ((c == 4) ? 512 : 1028 - c);
    int a = k << 2;
    return (c < 4) ? (a + c) : (1017 + c - a);
}
__device__ __forceinline__ int mir_of(int k, int c) {
    if (k == 0) return (c == 0 || c == 4) ? c : ((c < 4) ? c + 4 : c - 4);
    return 7 - c;
}

// Pass 1: row FFTs (four-step 32x32), output TRANSPOSED as packed bf16x2:
// spec_T[p][x][y]. p==0 blocks also build the geometry count hist; block
// (p==1, g==0) writes the twiddle table for fft_cols_hist as a side job.
__global__ __launch_bounds__(256, 4) void fft_rows(const float* __restrict__ in,
                                                   unsigned* __restrict__ spec,
                                                   float* __restrict__ cntp,
                                                   float2* __restrict__ tw) {
    __shared__ unsigned sh[SH_SIZE];
    __shared__ float hc[NBINS];
    int tid = threadIdx.x, blk = blockIdx.x;
    int p = blk >> 7, y0 = (blk & 127) << 3;
    if (p == 0)
        for (int i = tid; i < NBINS; i += 256) hc[i] = 0.f;
    int n1 = tid & 31, c = tid >> 5;
    const float* xr = in + (((size_t)(2 * p)) << 20) + ((size_t)(y0 + c) << 10);
    const float* yr = xr + (1u << 20);
    float2 r[32];
    #pragma unroll
    for (int j = 0; j < 32; ++j) {
        int n = n1 + (rev5(j) << 5);
        r[j] = make_float2(xr[n], yr[n]);
    }
    fft32(r);
    twiddle_rec(r, n1);
    int sb = 9 * n1 + c;
    #pragma unroll
    for (int k2 = 0; k2 < 32; ++k2) sh[sb + 289 * k2] = pk2(r[k2]);
    __syncthreads();
    int k2 = tid & 31;
    int rb = 289 * k2 + c;
    #pragma unroll
    for (int j = 0; j < 32; ++j) r[j] = up2(sh[rb + 9 * rev5(j)]);
    fft32(r);
    __syncthreads();
    int wb = 9 * k2 + c;
    #pragma unroll
    for (int k1 = 0; k1 < 32; ++k1) sh[wb + 289 * k1] = pk2(r[k1]);
    __syncthreads();
    unsigned* base = spec + (((size_t)p) << 20);
    for (int rep = 0; rep < 32; ++rep) {
        int idx = (rep << 8) + tid;
        int kcol = idx >> 3, cc = idx & 7;
        base[((size_t)kcol << 10) + y0 + cc] = sh[SLOT(kcol, cc)];
    }
    // ---- side job (p==1, g==0): twiddle table tw[32a+b] = W_1024^(a*b) ----
    if (blk == 128) {
        #pragma unroll
        for (int q = 0; q < 4; ++q) {
            int i = (tid << 2) + q;           // 0..1023
            int a = i >> 5, b = i & 31;
            float sn, cs;
            sincosf((float)(a * b) * -0.006135923151542565f, &sn, &cs);
            tw[i] = make_float2(cs, sn);
        }
    }
    // ---- counts phase (p==0 blocks only; uniform branch) ----
    if (p == 0) {
        int g = blk;                          // 0..127
        int row = (g << 2) + (tid >> 6);      // 4 rows/block, 0..511
        int xb = (tid & 63) << 4;             // run of 16 x
        int dy = row - 512, dy2 = dy * dy;
        int curbin = -1;
        float a = 0.f;
        #pragma unroll 4
        for (int j = 0; j < 16; ++j) {
            int x = xb + j;
            float w = 2.f;
            if (row == 0) w = (x > 512 || x == 0) ? 0.f : ((x == 512) ? 1.f : 2.f);
            int dx = x - 512;
            int bin = ibin(dy2 + dx * dx);
            if (bin == curbin) a += w;
            else {
                if (curbin >= 0 && a != 0.f) atomicAdd(&hc[curbin], a);
                curbin = bin; a = w;
            }
        }
        if (curbin >= 0 && a != 0.f) atomicAdd(&hc[curbin], a);
        if (g == 0) {                         // row 512
            int xb2 = tid << 2;
            int curb = -1;
            float aa = 0.f;
            #pragma unroll
            for (int j = 0; j < 4; ++j) {
                int xx = xb2 + j;
                if (xx > 512) continue;
                float w = ((xx & 511) == 0) ? 1.f : 2.f;
                int bin = 512 - xx;
                if (bin == curb) aa += w;
                else {
                    if (curb >= 0 && aa != 0.f) atomicAdd(&hc[curb], aa);
                    curb = bin; aa = w;
                }
            }
            if (curb >= 0 && aa != 0.f) atomicAdd(&hc[curb], aa);
        }
        __syncthreads();
        for (int i = tid; i < NBINS; i += 256)
            cntp[(size_t)g * NBINS + i] = hc[i];
    }
}

// Pass 2 (FUSED): column FFTs + Hermitian powers + radial hist, spectrum in
// packed bf16x2 throughout.
__global__ __launch_bounds__(256, 3) void fft_cols_hist(const unsigned* __restrict__ spec,
                                                        float* __restrict__ s2buf,
                                                        float* __restrict__ partial,
                                                        const float2* __restrict__ tw) {
    __shared__ unsigned sh[SH_SIZE];
    __shared__ float hs0[NBINS], hs1[NBINS];
    __shared__ float wred[8];
    int tid = threadIdx.x, blk = blockIdx.x;
    int p = blk >> 7, k = blk & 127;
    for (int i = tid; i < NBINS; i += 256) { hs0[i] = 0.f; hs1[i] = 0.f; }
    int n1 = tid & 31, c = tid >> 5;
    const unsigned* base = spec + (((size_t)p) << 20);
    const unsigned* colp = base + ((size_t)col_of(k, c) << 10);
    float2 r[32];
    #pragma unroll
    for (int j = 0; j < 32; ++j) r[j] = up2(colp[n1 + (rev5(j) << 5)]);
    fft32(r);
    twiddle_tab(r, n1, tw);
    int sb = 9 * n1 + c;
    #pragma unroll
    for (int q = 0; q < 32; ++q) sh[sb + 289 * q] = pk2(r[q]);
    __syncthreads();
    int k2 = tid & 31;
    int rb = 289 * k2 + c;
    #pragma unroll
    for (int j = 0; j < 32; ++j) r[j] = up2(sh[rb + 9 * rev5(j)]);
    __syncthreads();                      // exchange reads done; buffer reused
    fft32(r);
    // store full column spectrum: slot(k2 + 32*k1, c) = 9*k2 + c + 289*k1
    int wb = 9 * k2 + c;
    #pragma unroll
    for (int k1 = 0; k1 < 32; ++k1) sh[wb + 289 * k1] = pk2(r[k1]);
    __syncthreads();
    // ---- hist phase: cl = tid>>5 (column), chunk = tid&31 (16-ky run) ----
    const float inv = 1.0f / (float)NPIX;
    int cl = tid >> 5, chunk = tid & 31;
    int xcol = col_of(k, cl), mc = mir_of(k, cl);
    int dxv = xcol - 512, dx2 = dxv * dxv;
    bool xs = ((xcol & 511) == 0), xhi = (xcol > 512);
    float s2e = 0.f, s2o = 0.f;
    int curbin = -1;
    float a0 = 0.f, a1 = 0.f;
    int ky0 = chunk << 4;
    #pragma unroll 4
    for (int j = 0; j < 16; ++j) {
        int ky = ky0 + j;
        float w = 2.f;
        if (ky == 0) w = xhi ? 0.f : ((xcol == 0) ? 0.f : (xs ? 1.f : 2.f));
        int my = (1024 - ky) & 1023;
        float2 f1 = up2(sh[SLOT(ky, cl)]);
        float2 f2 = up2(sh[SLOT(my, mc)]);
        float xr = 0.5f * (f1.x + f2.x), xi = 0.5f * (f1.y - f2.y);
        float yr = 0.5f * (f1.y + f2.y), yi = 0.5f * (f2.x - f1.x);
        float pe = (xr * xr + xi * xi) * inv;
        float po = (yr * yr + yi * yi) * inv;
        int dy = ky - 512;
        int bin = ibin(dy * dy + dx2);
        float v0 = w * pe, v1 = w * po;
        s2e += v0 * pe;
        s2o += v1 * po;
        if (bin == curbin) { a0 += v0; a1 += v1; }
        else {
            if (curbin >= 0) { atomicAdd(&hs0[curbin], a0); atomicAdd(&hs1[curbin], a1); }
            curbin = bin; a0 = v0; a1 = v1;
        }
    }
    if (curbin >= 0) { atomicAdd(&hs0[curbin], a0); atomicAdd(&hs1[curbin], a1); }
    // ky = 512 row: one thread per column
    if ((tid & 31) == 0) {
        int cl2 = tid >> 5;
        int x2 = col_of(k, cl2);
        if (x2 <= 512) {
            int mc2 = mir_of(k, cl2);
            float w = ((x2 & 511) == 0) ? 1.f : 2.f;
            float2 f1 = up2(sh[SLOT(512, cl2)]);
            float2 f2 = up2(sh[SLOT(512, mc2)]);
            float xr = 0.5f * (f1.x + f2.x), xi = 0.5f * (f1.y - f2.y);
            float yr = 0.5f * (f1.y + f2.y), yi = 0.5f * (f2.x - f1.x);
            float pe = (xr * xr + xi * xi) * inv;
            float po = (yr * yr + yi * yi) * inv;
            float v0 = w * pe, v1 = w * po;
            s2e += v0 * pe;
            s2o += v1 * po;
            int bin = (x2 < 512) ? 512 - x2 : 0;   // dy = 0, exact
            atomicAdd(&hs0[bin], v0);
            atomicAdd(&hs1[bin], v1);
        }
    }
    #pragma unroll
    for (int off = 32; off > 0; off >>= 1) {
        s2e += __shfl_down(s2e, off);
        s2o += __shfl_down(s2o, off);
    }
    if ((tid & 63) == 0) { wred[tid >> 6] = s2e; wred[4 + (tid >> 6)] = s2o; }
    __syncthreads();
    if (tid == 0) s2buf[2 * blk]     = wred[0] + wred[1] + wred[2] + wred[3];
    if (tid == 1) s2buf[2 * blk + 1] = wred[4] + wred[5] + wred[6] + wred[7];
    // coalesced partial store: partial[b][k][bin], b = 2p / 2p+1
    float* pe = partial + ((size_t)(2 * p) * 128 + k) * NBINS;
    float* po = partial + ((size_t)(2 * p + 1) * 128 + k) * NBINS;
    for (int i = tid; i < NBINS; i += 256) {
        pe[i] = hs0[i];
        po[i] = hs1[i];
    }
}

// Pass 3 (coalesced bands): block = (b, 256-bin band). Loops over 128 value
// slices and 128 count slices; every load is a contiguous row segment.
__global__ __launch_bounds__(256) void reduce_loss(const float* __restrict__ partial,
                                                   const float* __restrict__ cntp,
                                                   float* __restrict__ rowval) {
    int b = blockIdx.x / 3, band = blockIdx.x % 3;
    int bin = band * 256 + threadIdx.x;
    if (bin >= NBINS) return;
    const float* bp = partial + (size_t)b * 128 * NBINS + bin;
    float s = 0.f;
    #pragma unroll 8
    for (int k = 0; k < 128; ++k) s += bp[(size_t)k * NBINS];
    float cv = 0.f;
    #pragma unroll 8
    for (int g = 0; g < 128; ++g) cv += cntp[(size_t)g * NBINS + bin];
    rowval[b * NBINS + bin] = (cv > 0.f) ? s * s / cv : 0.f;
}

// Final: out = WA/B * (sum s2buf - sum rowval)
__global__ __launch_bounds__(256) void final_out(const float* __restrict__ s2buf,
                                                 const float* __restrict__ rowval,
                                                 float* __restrict__ out) {
    __shared__ float red[256];
    int tid = threadIdx.x;
    float acc = 0.f;
    for (int i = tid; i < NB * NBINS; i += 256) acc -= rowval[i];
    for (int i = tid; i < 2 * NPAIR * 128; i += 256) acc += s2buf[i];
    red[tid] = acc;
    __syncthreads();
    for (int s = 128; s > 0; s >>= 1) {
        if (tid < s) red[tid] += red[tid + s];
        __syncthreads();
    }
    if (tid == 0) out[0] = red[0] * (0.002f / 16.0f);
}

extern "C" void kernel_launch(void* const* d_in, const int* in_sizes, int n_in,
                              void* d_out, int out_size, void* d_ws, size_t ws_size,
                              hipStream_t stream) {
    const float* in = (const float*)d_in[0];
    float* out = (float*)d_out;
    char* ws = (char*)d_ws;

    unsigned* spec = (unsigned*)ws;                               // 32 MiB (bf16x2)
    float* s2buf   = (float*)(ws + ((size_t)NPAIR << 20) * sizeof(unsigned));
    float* rowval  = s2buf + 2 * NPAIR * 128;                     // 2048
    float* cntp    = rowval + NB * NBINS;                         // 11600
    float* partial = cntp + 128 * NBINS;                          // 92800
    float2* tw     = (float2*)(partial + (size_t)NB * 128 * NBINS); // 1024 float2

    fft_rows<<<NPAIR * 128, 256, 0, stream>>>(in, spec, cntp, tw);
    fft_cols_hist<<<NPAIR * 128, 256, 0, stream>>>(spec, s2buf, partial, tw);
    reduce_loss<<<NB * 3, 256, 0, stream>>>(partial, cntp, rowval);
    final_out<<<1, 256, 0, stream>>>(s2buf, rowval, out);
}